// Round 1
// baseline (189.997 us; speedup 1.0000x reference)
//
#include <hip/hip_runtime.h>

// Problem constants (fixed by setup_inputs)
constexpr int BATCH = 8;
constexpr int NPB   = 1 << 20;       // N per batch
constexpr int BS    = 128;           // block_size
constexpr int NB    = NPB / BS;      // 8192 node-blocks per batch
constexpr int NBLK  = BATCH * NB;    // 65536 total node-blocks
constexpr int MAXKV = 32;

#define GRAPH_WEIGHT 0.3f

// Workspace layout (in floats):
//  [0, 512)      : sup partials, 64 slots x 8 floats  (slot: +0 sup_sum, +1 sup_cnt, +2 u_cnt)
//  [512, 1536)   : graph partials, 8 b x 16 slots x 8 floats (+0 loss, +1 count)
//  [0, 2048)     : zeroed by hipMemsetAsync each call
//  [2048, ...)   : per-block stats (fully overwritten by phase 1)
constexpr int WS_SUP   = 0;
constexpr int WS_GRAPH = 512;
constexpr int WS_ZERO  = 2048;          // floats to zero
constexpr int WS_BSUM  = 2048;          // sum of keep*p per block
constexpr int WS_BCNT  = WS_BSUM + NBLK;
constexpr int WS_QCNT  = WS_BCNT + NBLK;
constexpr int WS_UP    = WS_QCNT + NBLK; // sum of u*p
constexpr int WS_UP2   = WS_UP  + NBLK;  // sum of u*p^2

// ---------------- Phase 1: per-element pass + per-block stats ----------------
// 4 elements/thread (float4/int4, 16B loads). One 32-lane half-wave covers one
// 128-element node-block, so block sums reduce with xor-shuffles <=16.
__global__ __launch_bounds__(256) void k_phase1(const float* __restrict__ lg,
                                                const float* __restrict__ tg,
                                                const int* __restrict__ sm,
                                                const int* __restrict__ im,
                                                float* __restrict__ ws)
{
    const int tid = blockIdx.x * 256 + threadIdx.x;
    const int e0  = tid << 2;

    const float4 x4 = *reinterpret_cast<const float4*>(lg + e0);
    const float4 t4 = *reinterpret_cast<const float4*>(tg + e0);
    const int4   s4 = *reinterpret_cast<const int4*>(sm + e0);
    const int4   g4 = *reinterpret_cast<const int4*>(im + e0);

    const float xs[4] = {x4.x, x4.y, x4.z, x4.w};
    const float ts[4] = {t4.x, t4.y, t4.z, t4.w};
    const int   ssv[4] = {s4.x, s4.y, s4.z, s4.w};
    const int   ggv[4] = {g4.x, g4.y, g4.z, g4.w};

    float sup_sum = 0.f, sup_cnt = 0.f, u_cnt = 0.f;
    float bsum = 0.f, bcnt = 0.f, q = 0.f, up = 0.f, up2 = 0.f;

#pragma unroll
    for (int j = 0; j < 4; ++j) {
        const float x = xs[j], t = ts[j];
        const bool s = (ssv[j] != 0);
        const bool g = (ggv[j] != 0);

        const float ax  = fabsf(x);
        const float e   = __expf(-ax);           // e in (0,1]
        const float lp  = __logf(1.f + e);       // log1p(exp(-|x|))
        const float per = fmaxf(x, 0.f) - x * t + lp;
        const float inv = 1.f / (1.f + e);
        const float p   = (x >= 0.f) ? inv : e * inv;   // sigmoid(x)

        if (s) { sup_sum += per; sup_cnt += 1.f; }
        if (!g) { bsum += p; bcnt += 1.f; }
        if (!g && !s) { q += 1.f; up += p; up2 += p * p; u_cnt += 1.f; }
    }

    // 32-lane (half-wave) reduction: block-local quantities
#pragma unroll
    for (int d = 16; d >= 1; d >>= 1) {
        bsum += __shfl_xor(bsum, d);
        bcnt += __shfl_xor(bcnt, d);
        q    += __shfl_xor(q, d);
        up   += __shfl_xor(up, d);
        up2  += __shfl_xor(up2, d);
    }
    const int lane = threadIdx.x & 63;
    if ((lane & 31) == 0) {
        const int blk = ((tid >> 6) << 1) + (lane >> 5);  // node-block id
        ws[WS_BSUM + blk] = bsum;
        ws[WS_BCNT + blk] = bcnt;
        ws[WS_QCNT + blk] = q;
        ws[WS_UP   + blk] = up;
        ws[WS_UP2  + blk] = up2;
    }

    // full-wave reduction for global sup/uncertain accumulators
#pragma unroll
    for (int d = 32; d >= 1; d >>= 1) {
        sup_sum += __shfl_xor(sup_sum, d);
        sup_cnt += __shfl_xor(sup_cnt, d);
        u_cnt   += __shfl_xor(u_cnt, d);
    }
    __shared__ float lds[4][3];
    const int w = threadIdx.x >> 6;
    if (lane == 0) { lds[w][0] = sup_sum; lds[w][1] = sup_cnt; lds[w][2] = u_cnt; }
    __syncthreads();
    if (threadIdx.x == 0) {
        const float a = lds[0][0] + lds[1][0] + lds[2][0] + lds[3][0];
        const float b = lds[0][1] + lds[1][1] + lds[2][1] + lds[3][1];
        const float c = lds[0][2] + lds[1][2] + lds[2][2] + lds[3][2];
        float* slot = ws + WS_SUP + (int)(blockIdx.x & 63) * 8; // 64-way striping
        atomicAdd(slot + 0, a);
        atomicAdd(slot + 1, b);
        atomicAdd(slot + 2, c);
    }
}

// ---------------- Phase 2: neighbor gather per node-block ----------------
// One 32-lane half-wave per node-block; lane k handles neighbor k (coalesced
// kv_indices read; block-sum gathers hit a 64KB/batch L1/L2-resident table).
__global__ __launch_bounds__(256) void k_phase2(const int* __restrict__ kvi,
                                                const int* __restrict__ kvn,
                                                float* __restrict__ ws)
{
    const int tid    = blockIdx.x * 256 + threadIdx.x;
    const int h      = tid >> 5;            // node-block id, 0..NBLK-1
    const int lane32 = threadIdx.x & 31;
    const int b      = h >> 13;             // NB = 8192

    const int nkv = kvn[h];                 // broadcast load
    const int idx = kvi[(size_t)h * MAXKV + lane32];

    const float* bsum_a = ws + WS_BSUM;
    const float* bcnt_a = ws + WS_BCNT;

    float gs = 0.f, gc = 0.f;
    if (lane32 < nkv) {
        const int src = (h & ~(NB - 1)) + idx;   // b*NB + idx
        gs = bsum_a[src];
        gc = bcnt_a[src];
    }
#pragma unroll
    for (int d = 16; d >= 1; d >>= 1) {
        gs += __shfl_xor(gs, d);
        gc += __shfl_xor(gc, d);
    }

    __shared__ float lds[8][2];
    if (lane32 == 0) {
        const float q   = ws[WS_QCNT + h];
        const float up  = ws[WS_UP   + h];
        const float up2 = ws[WS_UP2  + h];
        const float m   = gs / fmaxf(gc, 1.f);
        const bool  vb  = (q > 0.f) && (nkv > 0) && (gc > 0.f);
        // sum_u (p - m)^2 = sum_u p^2 - 2m sum_u p + m^2 * q
        const float sq  = up2 - 2.f * m * up + m * m * q;
        const int hw = threadIdx.x >> 5;
        lds[hw][0] = vb ? sq : 0.f;
        lds[hw][1] = vb ? q  : 0.f;
    }
    __syncthreads();
    if (threadIdx.x == 0) {
        float L = 0.f, C = 0.f;
#pragma unroll
        for (int j = 0; j < 8; ++j) { L += lds[j][0]; C += lds[j][1]; }
        float* slot = ws + WS_GRAPH + b * 128 + (int)(blockIdx.x & 15) * 8;
        atomicAdd(slot + 0, L);
        atomicAdd(slot + 1, C);
    }
}

// ---------------- Phase 3: final scalar ----------------
__global__ __launch_bounds__(64) void k_phase3(const float* __restrict__ ws,
                                               float* __restrict__ out)
{
    const int lane = threadIdx.x;  // 0..63

    float ss = ws[WS_SUP + lane * 8 + 0];
    float sc = ws[WS_SUP + lane * 8 + 1];
    float uc = ws[WS_SUP + lane * 8 + 2];
#pragma unroll
    for (int d = 32; d >= 1; d >>= 1) {
        ss += __shfl_xor(ss, d);
        sc += __shfl_xor(sc, d);
        uc += __shfl_xor(uc, d);
    }

    float per_sum = 0.f, nvalid = 0.f;
    for (int b = 0; b < BATCH; ++b) {
        float l = 0.f, c = 0.f;
        if (lane < 16) {
            l = ws[WS_GRAPH + b * 128 + lane * 8 + 0];
            c = ws[WS_GRAPH + b * 128 + lane * 8 + 1];
        }
#pragma unroll
        for (int d = 32; d >= 1; d >>= 1) {
            l += __shfl_xor(l, d);
            c += __shfl_xor(c, d);
        }
        if (c > 0.f) { per_sum += l / fmaxf(c, 1.f); nvalid += 1.f; }
    }

    if (lane == 0) {
        const float loss_sup = (sc > 0.f) ? ss / fmaxf(sc, 1.f) : 0.f;
        float lg = per_sum / fmaxf(nvalid, 1.f);
        if (!(uc > 0.f)) lg = 0.f;
        out[0] = loss_sup + GRAPH_WEIGHT * lg;
    }
}

extern "C" void kernel_launch(void* const* d_in, const int* in_sizes, int n_in,
                              void* d_out, int out_size, void* d_ws, size_t ws_size,
                              hipStream_t stream) {
    const float* lg  = (const float*)d_in[0];  // logits  [B,N,1]
    const float* tg  = (const float*)d_in[1];  // targets [B,N]
    const int*   sm  = (const int*)d_in[2];    // sup_mask (bool -> int32)
    const int*   im  = (const int*)d_in[3];    // ignore_mask (bool -> int32)
    const int*   kvi = (const int*)d_in[4];    // kv_indices [B,NB,MAXKV]
    const int*   kvn = (const int*)d_in[5];    // kv_num_blocks [B,NB]
    float* ws  = (float*)d_ws;
    float* out = (float*)d_out;

    hipMemsetAsync(d_ws, 0, WS_ZERO * sizeof(float), stream);

    // Phase 1: 8.39M elements, 4 per thread -> 8192 workgroups of 256
    k_phase1<<<(BATCH * NPB) / (4 * 256), 256, 0, stream>>>(lg, tg, sm, im, ws);
    // Phase 2: 65536 node-blocks, 32 lanes each -> 8192 workgroups of 256
    k_phase2<<<(NBLK * 32) / 256, 256, 0, stream>>>(kvi, kvn, ws);
    // Phase 3: single wave
    k_phase3<<<1, 64, 0, stream>>>(ws, out);
}